// Round 8
// baseline (811.916 us; speedup 1.0000x reference)
//
#include <hip/hip_runtime.h>
#include <hip/hip_fp16.h>

// RNAGNN round 14: src-range-partitioned two-pass gather (L2-resident halves).
// csr additionally splits each node's edge run into lo-src/hi-src segments
// (rowmid). Pass A gathers the lo half (z rows 0..N/2 = 3.2 MB, fits 4MB/XCD
// L2) into fp32 partials pp; pass B gathers the hi half, adds pp + self-loop,
// runs the round-10 epilogues. col reads are nontemporal to avoid evicting z.

#define DIM 16
#define F_IN 64
#define BUCK_SHIFT 10
#define BUCK_SIZE 1024
#define MAXB 256            // nb = ceil(200000/1024) = 196
#define HIST_CHUNK 4096
#define BIN_CHUNK 8192
#define EPB 32              // edges per thread in bin (8192/256)
#define CSR_CAP 33280       // staging words; fallback beyond

// LDS weight layout: W[f][j] at f*17+j -> lanes with distinct f hit distinct banks
#define WA_OFF 0
#define WB_OFF 272
#define BA_OFF 544
#define BB_OFF 560
#define SW_SIZE 576
#define WIDX(f, j) ((f) * 17 + (j))

// ---------------- per-bucket edge histogram ----------------

__global__ void hist_kernel(const int* __restrict__ dst, int* __restrict__ ghist,
                            int E, int nb) {
    __shared__ int lh[MAXB];
    int t = threadIdx.x;
    for (int i = t; i < nb; i += 256) lh[i] = 0;
    __syncthreads();
    int base = blockIdx.x * HIST_CHUNK;
    int end = min(base + HIST_CHUNK, E);
    for (int e = base + t; e < end; e += 256) atomicAdd(&lh[dst[e] >> BUCK_SHIFT], 1);
    __syncthreads();
    for (int b = t; b < nb; b += 256) {
        int c = lh[b];
        if (c) atomicAdd(&ghist[b], c);
    }
}

// exclusive scan of ghist (nb <= 256) -> boff, cursor
__global__ void scan_kernel(const int* __restrict__ ghist, int* __restrict__ boff,
                            int* __restrict__ cursor, int nb, int E) {
    __shared__ int sd[256];
    int t = threadIdx.x;
    int v = (t < nb) ? ghist[t] : 0;
    sd[t] = v;
    __syncthreads();
    for (int off = 1; off < 256; off <<= 1) {
        int u = (t >= off) ? sd[t - off] : 0;
        __syncthreads();
        sd[t] += u;
        __syncthreads();
    }
    if (t < nb) {
        int excl = sd[t] - v;
        boff[t] = excl;
        cursor[t] = excl;
    }
    if (t == 255) boff[nb] = E;
}

// pass A: bin edges into dst-range buckets; packed = src | (local_dst << 18).
__launch_bounds__(256)
__global__ void bin_kernel(const int* __restrict__ src, const int* __restrict__ dst,
                           int* __restrict__ cursor, unsigned* __restrict__ packed,
                           int E, int nb) {
    __shared__ unsigned sedge[BIN_CHUNK];
    __shared__ unsigned char sbid[BIN_CHUNK];
    __shared__ int lh[MAXB];
    __shared__ int sd[MAXB];
    __shared__ int lstart[MAXB];
    __shared__ int lrank[MAXB];
    __shared__ int gbase[MAXB];

    int t = threadIdx.x;
    int base = blockIdx.x * BIN_CHUNK;
    int end = min(base + BIN_CHUNK, E);
    lh[t] = 0;
    __syncthreads();

    unsigned pv[EPB];
    int bk[EPB];
#pragma unroll
    for (int i = 0; i < EPB; ++i) {
        int e = base + t + i * 256;
        if (e < end) {
            int d = dst[e];
            int b = d >> BUCK_SHIFT;
            pv[i] = (unsigned)src[e] | ((unsigned)(d & (BUCK_SIZE - 1)) << 18);
            bk[i] = b;
            atomicAdd(&lh[b], 1);
        } else {
            bk[i] = -1;
            pv[i] = 0u;
        }
    }
    __syncthreads();

    int v = (t < nb) ? lh[t] : 0;
    sd[t] = v;
    __syncthreads();
    for (int off = 1; off < 256; off <<= 1) {
        int u = (t >= off) ? sd[t - off] : 0;
        __syncthreads();
        sd[t] += u;
        __syncthreads();
    }
    if (t < nb) {
        lstart[t] = sd[t] - v;
        lrank[t] = 0;
        gbase[t] = v ? atomicAdd(&cursor[t], v) : 0;
    }
    __syncthreads();

#pragma unroll
    for (int i = 0; i < EPB; ++i) {
        int b = bk[i];
        if (b >= 0) {
            int rank = atomicAdd(&lrank[b], 1);
            int p = lstart[b] + rank;
            sedge[p] = pv[i];
            sbid[p] = (unsigned char)b;
        }
    }
    __syncthreads();

    int total = end - base;
    for (int j = t; j < total; j += 256) {
        int b = sbid[j];
        packed[(size_t)gbase[b] + (unsigned)(j - lstart[b])] = sedge[j];
    }
}

// pass B: bucket -> CSR with per-node lo/hi src partition (rowmid).
// Dynamic LDS: sstage[CSR_CAP] (sd aliases it) + cnt/cl/scur/scur2 [1024 each].
__launch_bounds__(1024)
__global__ void csr_kernel(const unsigned* __restrict__ packed, const int* __restrict__ boff,
                           int* __restrict__ rowptr, int* __restrict__ rowmid,
                           float* __restrict__ dinv,
                           int* __restrict__ col, int N, int E, int NH) {
    extern __shared__ unsigned smem[];
    unsigned* sstage = smem;                 // CSR_CAP words (sd aliases first 1024)
    int* sd    = (int*)smem;
    int* cnt   = (int*)(smem + CSR_CAP);
    int* cl    = cnt + BUCK_SIZE;
    int* scur  = cl + BUCK_SIZE;
    int* scur2 = scur + BUCK_SIZE;

    int t = threadIdx.x, blk = blockIdx.x;
    cnt[t] = 0;
    cl[t] = 0;
    __syncthreads();
    int b0 = boff[blk], e1 = boff[blk + 1];
    for (int e = b0 + t; e < e1; e += 1024) {
        unsigned k = packed[e];
        int ln = k >> 18;
        atomicAdd(&cnt[ln], 1);
        if ((int)(k & 0x3FFFFu) < NH) atomicAdd(&cl[ln], 1);
    }
    __syncthreads();
    int d = cnt[t];
    sd[t] = d;
    __syncthreads();
    for (int off = 1; off < 1024; off <<= 1) {
        int v = (t >= off) ? sd[t - off] : 0;
        __syncthreads();
        sd[t] += v;
        __syncthreads();
    }
    int lstart = sd[t] - d;                  // 0-based within bucket
    int dlo = cl[t];
    int i = (blk << BUCK_SHIFT) + t;
    if (i < N) {
        rowptr[i] = b0 + lstart;
        rowmid[i] = b0 + lstart + dlo;
        dinv[i] = rsqrtf((float)(d + 1));    // +1 = self loop
        if (i == N - 1) rowptr[N] = E;
    }
    scur[t] = lstart;
    scur2[t] = lstart + dlo;
    __syncthreads();                         // sd reads done before staging overwrites
    for (int e = b0 + t; e < e1; e += 1024) {
        unsigned k = packed[e];
        int ln = k >> 18;
        int s = (int)(k & 0x3FFFFu);
        int pos = (s < NH) ? atomicAdd(&scur[ln], 1) : atomicAdd(&scur2[ln], 1);
        if (pos < CSR_CAP) sstage[pos] = (unsigned)s;
        else col[(size_t)b0 + pos] = s;      // overflow fallback (rare)
    }
    __syncthreads();
    int total = e1 - b0;
    int lim = min(total, CSR_CAP);
    for (int j = t; j < lim; j += 1024) col[(size_t)b0 + j] = sstage[j];
}

// ---------------- z0 = dinv * (x @ W_in), interleaved 16-feat fp16 table ----------------

__global__ void z0_kernel(const float* __restrict__ x, const float* __restrict__ W,
                          const float* __restrict__ dinv,
                          __half* __restrict__ z, int n) {
    __shared__ float sW[F_IN * DIM];
    int t = threadIdx.x;
#pragma unroll
    for (int j = 0; j < 4; ++j) sW[t + j * 256] = W[t + j * 256];
    __syncthreads();
    int idx = blockIdx.x * 256 + t;
    if (idx >= n * 2) return;
    int node = idx >> 1, p = idx & 1;
    float acc[8] = {0, 0, 0, 0, 0, 0, 0, 0};
    const float4* xr = (const float4*)(x + (size_t)node * F_IN);
#pragma unroll
    for (int k4 = 0; k4 < 16; ++k4) {
        float4 xv = xr[k4];
        float c[4] = { xv.x, xv.y, xv.z, xv.w };
#pragma unroll
        for (int cc = 0; cc < 4; ++cc) {
            const float* wr = &sW[(k4 * 4 + cc) * DIM + p * 8];
#pragma unroll
            for (int j = 0; j < 8; ++j) acc[j] += c[cc] * wr[j];
        }
    }
    float di = dinv[node];
    __half2 o[4];
#pragma unroll
    for (int m = 0; m < 4; ++m) o[m] = __floats2half2_rn(di * acc[2 * m], di * acc[2 * m + 1]);
    *(float4*)(z + ((size_t)node << 4) + p * 8) = *(float4*)o;
}

// ---------------- pass A: gather lo-src half -> fp32 partials pp ----------------

__launch_bounds__(256)
__global__ void gatherP_kernel(const int* __restrict__ rowptr, const int* __restrict__ rowmid,
                               const int* __restrict__ col, const __half* __restrict__ z,
                               float* __restrict__ pp, int N) {
    int idx = blockIdx.x * 256 + threadIdx.x;
    int node = idx >> 3, o = idx & 7;          // 8 lanes per node
    bool alive = node < N;
    float a[16];
#pragma unroll
    for (int j = 0; j < 16; ++j) a[j] = 0.f;
    if (alive) {
        int start = rowptr[node];
        int len = rowmid[node] - start;        // lo segment
        int k = o;
        for (; k + 8 < len; k += 16) {
            int s0 = __builtin_nontemporal_load(col + start + k);
            int s1 = __builtin_nontemporal_load(col + start + k + 8);
            const float4* q0 = (const float4*)(z + ((size_t)s0 << 4));
            const float4* q1 = (const float4*)(z + ((size_t)s1 << 4));
            float4 v0l = q0[0], v0h = q0[1];
            float4 v1l = q1[0], v1h = q1[1];
            const __half2* h0l = (const __half2*)&v0l;
            const __half2* h0h = (const __half2*)&v0h;
            const __half2* h1l = (const __half2*)&v1l;
            const __half2* h1h = (const __half2*)&v1h;
#pragma unroll
            for (int m = 0; m < 4; ++m) {
                float2 f0 = __half22float2(h0l[m]);
                float2 f1 = __half22float2(h1l[m]);
                a[2 * m] += f0.x + f1.x;
                a[2 * m + 1] += f0.y + f1.y;
                float2 g0 = __half22float2(h0h[m]);
                float2 g1 = __half22float2(h1h[m]);
                a[8 + 2 * m] += g0.x + g1.x;
                a[8 + 2 * m + 1] += g0.y + g1.y;
            }
        }
        if (k < len) {
            int s = __builtin_nontemporal_load(col + start + k);
            const float4* q = (const float4*)(z + ((size_t)s << 4));
            float4 vl = q[0], vh = q[1];
            const __half2* hl = (const __half2*)&vl;
            const __half2* hh = (const __half2*)&vh;
#pragma unroll
            for (int m = 0; m < 4; ++m) {
                float2 f2 = __half22float2(hl[m]);
                a[2 * m] += f2.x; a[2 * m + 1] += f2.y;
                float2 g2 = __half22float2(hh[m]);
                a[8 + 2 * m] += g2.x; a[8 + 2 * m + 1] += g2.y;
            }
        }
    }
#pragma unroll
    for (int j = 0; j < 16; ++j) {
        a[j] += __shfl_xor(a[j], 1);
        a[j] += __shfl_xor(a[j], 2);
        a[j] += __shfl_xor(a[j], 4);
    }
    if (alive && o < 4) {
        float4 w = make_float4(0.f, 0.f, 0.f, 0.f);
#pragma unroll
        for (int j = 0; j < 4; ++j)
            if (o == j) w = make_float4(a[4 * j], a[4 * j + 1], a[4 * j + 2], a[4 * j + 3]);
        *(float4*)(pp + ((size_t)node << 4) + (o << 2)) = w;
    }
}

// ---------------- pass B: gather hi-src half + partial + self-loop + epilogue ----------------
// MODE 0 : znext = fp16(di*(r + b))          (layer 0)
// MODE 1 : matmul -> o1 (pre-BN fp32) + BN partials -> bnsum replica
// MODE 3 : dual matmul + ReLU -> o1, o2 (heads)

template <int MODE>
__launch_bounds__(256)
__global__ void gatherE_kernel(const int* __restrict__ rowptr, const int* __restrict__ rowmid,
                               const int* __restrict__ col, const __half* __restrict__ z,
                               const float* __restrict__ dinv, const float* __restrict__ pp,
                               const float* __restrict__ Wa, const float* __restrict__ Wb,
                               const float* __restrict__ ba, const float* __restrict__ bb,
                               float* __restrict__ o1, float* __restrict__ o2,
                               __half* __restrict__ znext, float* __restrict__ bnsum, int N) {
    __shared__ float sW[SW_SIZE];
    __shared__ float sred[4][32];
    int t = threadIdx.x;
    if (MODE == 1 || MODE == 3) {
        int f = t >> 4, j = t & 15;
        sW[WA_OFF + WIDX(f, j)] = Wa[t];
        if (MODE == 3) sW[WB_OFF + WIDX(f, j)] = Wb[t];
        if (t < 16) {
            sW[BA_OFF + t] = ba[t];
            if (MODE == 3) sW[BB_OFF + t] = bb[t];
        }
        __syncthreads();
    } else {
        if (t < 16) sW[BA_OFF + t] = ba[t];
        __syncthreads();
    }

    int idx = blockIdx.x * 256 + t;
    int node = idx >> 3, o = idx & 7;          // 8 lanes per node
    bool alive = node < N;
    float a[16];
#pragma unroll
    for (int j = 0; j < 16; ++j) a[j] = 0.f;
    float di = 0.f;
    if (alive) {
        di = dinv[node];
        int start = rowmid[node];              // hi segment
        int len = rowptr[node + 1] - start;
        int k = o;
        for (; k + 8 < len; k += 16) {
            int s0 = __builtin_nontemporal_load(col + start + k);
            int s1 = __builtin_nontemporal_load(col + start + k + 8);
            const float4* q0 = (const float4*)(z + ((size_t)s0 << 4));
            const float4* q1 = (const float4*)(z + ((size_t)s1 << 4));
            float4 v0l = q0[0], v0h = q0[1];
            float4 v1l = q1[0], v1h = q1[1];
            const __half2* h0l = (const __half2*)&v0l;
            const __half2* h0h = (const __half2*)&v0h;
            const __half2* h1l = (const __half2*)&v1l;
            const __half2* h1h = (const __half2*)&v1h;
#pragma unroll
            for (int m = 0; m < 4; ++m) {
                float2 f0 = __half22float2(h0l[m]);
                float2 f1 = __half22float2(h1l[m]);
                a[2 * m] += f0.x + f1.x;
                a[2 * m + 1] += f0.y + f1.y;
                float2 g0 = __half22float2(h0h[m]);
                float2 g1 = __half22float2(h1h[m]);
                a[8 + 2 * m] += g0.x + g1.x;
                a[8 + 2 * m + 1] += g0.y + g1.y;
            }
        }
        if (k < len) {
            int s = __builtin_nontemporal_load(col + start + k);
            const float4* q = (const float4*)(z + ((size_t)s << 4));
            float4 vl = q[0], vh = q[1];
            const __half2* hl = (const __half2*)&vl;
            const __half2* hh = (const __half2*)&vh;
#pragma unroll
            for (int m = 0; m < 4; ++m) {
                float2 f2 = __half22float2(hl[m]);
                a[2 * m] += f2.x; a[2 * m + 1] += f2.y;
                float2 g2 = __half22float2(hh[m]);
                a[8 + 2 * m] += g2.x; a[8 + 2 * m + 1] += g2.y;
            }
        }
    }
#pragma unroll
    for (int j = 0; j < 16; ++j) {
        a[j] += __shfl_xor(a[j], 1);
        a[j] += __shfl_xor(a[j], 2);
        a[j] += __shfl_xor(a[j], 4);
    }
    if (alive) {
        // lo-half partial (all 8 lanes read same row -> broadcast)
        const float4* ppr = (const float4*)(pp + ((size_t)node << 4));
        float4 p0 = ppr[0], p1 = ppr[1], p2 = ppr[2], p3 = ppr[3];
        a[0] += p0.x; a[1] += p0.y; a[2] += p0.z; a[3] += p0.w;
        a[4] += p1.x; a[5] += p1.y; a[6] += p1.z; a[7] += p1.w;
        a[8] += p2.x; a[9] += p2.y; a[10] += p2.z; a[11] += p2.w;
        a[12] += p3.x; a[13] += p3.y; a[14] += p3.z; a[15] += p3.w;
        // self loop
        const float4* q = (const float4*)(z + ((size_t)node << 4));
        float4 vl = q[0], vh = q[1];
        const __half2* hl = (const __half2*)&vl;
        const __half2* hh = (const __half2*)&vh;
#pragma unroll
        for (int m = 0; m < 4; ++m) {
            float2 f2 = __half22float2(hl[m]);
            a[2 * m] += f2.x; a[2 * m + 1] += f2.y;
            float2 g2 = __half22float2(hh[m]);
            a[8 + 2 * m] += g2.x; a[8 + 2 * m + 1] += g2.y;
        }
    }
    float r[16];
#pragma unroll
    for (int j = 0; j < 16; ++j) r[j] = di * a[j];

    if (MODE == 0) {
        if (alive && o == 0) {
            __half2 ov[8];
#pragma unroll
            for (int m = 0; m < 8; ++m)
                ov[m] = __floats2half2_rn(di * (r[2 * m] + sW[BA_OFF + 2 * m]),
                                          di * (r[2 * m + 1] + sW[BA_OFF + 2 * m + 1]));
            *(float4*)(znext + ((size_t)node << 4)) = ((float4*)ov)[0];
            *(float4*)(znext + ((size_t)node << 4) + 8) = ((float4*)ov)[1];
        }
        return;
    }

    // MODE 1 / 3: lane o owns input feats {2o, 2o+1}
    float rc0 = 0.f, rc1 = 0.f;
#pragma unroll
    for (int j = 0; j < 8; ++j)
        if (o == j) { rc0 = r[2 * j]; rc1 = r[2 * j + 1]; }
    if (!alive) { rc0 = 0.f; rc1 = 0.f; }
    int f0 = 2 * o;
    float pa[16];
#pragma unroll
    for (int j = 0; j < 16; ++j)
        pa[j] = rc0 * sW[WA_OFF + WIDX(f0, j)] + rc1 * sW[WA_OFF + WIDX(f0 + 1, j)];
#pragma unroll
    for (int j = 0; j < 16; ++j) {
        pa[j] += __shfl_xor(pa[j], 1);
        pa[j] += __shfl_xor(pa[j], 2);
        pa[j] += __shfl_xor(pa[j], 4);
    }

    if (MODE == 1) {
        float o0 = 0.f, o1v = 0.f;
#pragma unroll
        for (int j = 0; j < 8; ++j)
            if (o == j) {
                o0 = pa[2 * j] + sW[BA_OFF + 2 * j];
                o1v = pa[2 * j + 1] + sW[BA_OFF + 2 * j + 1];
            }
        if (alive)
            *(float2*)(o1 + ((size_t)node << 4) + 2 * o) = make_float2(o0, o1v);
        float s0 = alive ? o0 : 0.f, s1 = alive ? o1v : 0.f;
        float q0 = s0 * s0, q1 = s1 * s1;
#pragma unroll
        for (int m = 8; m <= 32; m <<= 1) {
            s0 += __shfl_xor(s0, m); s1 += __shfl_xor(s1, m);
            q0 += __shfl_xor(q0, m); q1 += __shfl_xor(q1, m);
        }
        int lane = t & 63, wave = t >> 6;
        if (lane < 8) {
            sred[wave][2 * lane] = s0;
            sred[wave][2 * lane + 1] = s1;
            sred[wave][16 + 2 * lane] = q0;
            sred[wave][16 + 2 * lane + 1] = q1;
        }
        __syncthreads();
        if (t < 32) {
            float v = sred[0][t] + sred[1][t] + sred[2][t] + sred[3][t];
            atomicAdd(&bnsum[(blockIdx.x & 7) * 32 + t], v);
        }
        return;
    }

    // MODE 3: dual heads
    {
        float pb[16];
#pragma unroll
        for (int j = 0; j < 16; ++j)
            pb[j] = rc0 * sW[WB_OFF + WIDX(f0, j)] + rc1 * sW[WB_OFF + WIDX(f0 + 1, j)];
#pragma unroll
        for (int j = 0; j < 16; ++j) {
            pb[j] += __shfl_xor(pb[j], 1);
            pb[j] += __shfl_xor(pb[j], 2);
            pb[j] += __shfl_xor(pb[j], 4);
        }
        if (alive) {
            float oa0 = 0.f, oa1 = 0.f, ob0 = 0.f, ob1 = 0.f;
#pragma unroll
            for (int j = 0; j < 8; ++j)
                if (o == j) {
                    oa0 = fmaxf(pa[2 * j] + sW[BA_OFF + 2 * j], 0.f);
                    oa1 = fmaxf(pa[2 * j + 1] + sW[BA_OFF + 2 * j + 1], 0.f);
                    ob0 = fmaxf(pb[2 * j] + sW[BB_OFF + 2 * j], 0.f);
                    ob1 = fmaxf(pb[2 * j + 1] + sW[BB_OFF + 2 * j + 1], 0.f);
                }
            *(float2*)(o1 + ((size_t)node << 4) + 2 * o) = make_float2(oa0, oa1);
            *(float2*)(o2 + ((size_t)node << 4) + 2 * o) = make_float2(ob0, ob1);
        }
    }
}

// ---------------- BN finalize (8 replicas -> scale/shift) ----------------

__global__ void bnfin_kernel(const float* __restrict__ bnsum, const float* __restrict__ gamma,
                             const float* __restrict__ beta, float* __restrict__ ssout, int n) {
    int t = threadIdx.x;
    if (t >= 16) return;
    float s = 0.f, sq = 0.f;
#pragma unroll
    for (int rep = 0; rep < 8; ++rep) {
        s += bnsum[rep * 32 + t];
        sq += bnsum[rep * 32 + 16 + t];
    }
    float invN = 1.f / (float)n;
    float mean = s * invN;
    float var = fmaxf(sq * invN - mean * mean, 0.f);
    float scale = gamma[t] * rsqrtf(var + 1e-5f);
    ssout[t] = scale;
    ssout[16 + t] = beta[t] - mean * scale;
}

// ---------------- BN apply + ReLU -> next interleaved z table ----------------

__global__ void bn_relu_z_kernel(const float* __restrict__ hp, const float* __restrict__ ss,
                                 const float* __restrict__ dinv,
                                 __half* __restrict__ z, int n) {
    int idx = blockIdx.x * 256 + threadIdx.x;
    if (idx >= n * 2) return;
    int node = idx >> 1, p = idx & 1;
    float di = dinv[node];
    const float4* hr = (const float4*)(hp + ((size_t)node << 4) + p * 8);
    float4 v0 = hr[0], v1 = hr[1];
    float vv[8] = { v0.x, v0.y, v0.z, v0.w, v1.x, v1.y, v1.z, v1.w };
    __half2 o[4];
#pragma unroll
    for (int m = 0; m < 4; ++m) {
        int f0 = p * 8 + 2 * m;
        float r0 = di * fmaxf(vv[2 * m] * ss[f0] + ss[16 + f0], 0.f);
        float r1 = di * fmaxf(vv[2 * m + 1] * ss[f0 + 1] + ss[16 + f0 + 1], 0.f);
        o[m] = __floats2half2_rn(r0, r1);
    }
    *(float4*)(z + ((size_t)node << 4) + p * 8) = *(float4*)o;
}

// ---------------- launcher ----------------

extern "C" void kernel_launch(void* const* d_in, const int* in_sizes, int n_in,
                              void* d_out, int out_size, void* d_ws, size_t ws_size,
                              hipStream_t stream) {
    (void)n_in; (void)out_size; (void)ws_size;
    const float* x      = (const float*)d_in[0];
    const int*   edge   = (const int*)d_in[1];
    const float* W_in   = (const float*)d_in[2];
    const float* b_in   = (const float*)d_in[3];
    const float* Ws     = (const float*)d_in[4];
    const float* bs     = (const float*)d_in[5];
    const float* gammas = (const float*)d_in[6];
    const float* betas  = (const float*)d_in[7];
    const float* W_sin  = (const float*)d_in[8];
    const float* b_sin  = (const float*)d_in[9];
    const float* W_cos  = (const float*)d_in[10];
    const float* b_cos  = (const float*)d_in[11];
    float* out = (float*)d_out;

    const int N = in_sizes[0] / F_IN;          // 200000
    const int E = in_sizes[1] / 2;             // 6400000
    const int L = in_sizes[4] / (DIM * DIM);   // 4
    const int nb = (N + BUCK_SIZE - 1) >> BUCK_SHIFT;   // 196
    const int NH = N >> 1;                     // src split point
    const int* src = edge;
    const int* dst = edge + E;

    char* ws = (char*)d_ws;
    size_t off = 0;
    auto alloc = [&](size_t bytes) { char* p = ws + off; off += (bytes + 15) & ~size_t(15); return p; };
    float*    dinv   = (float*)alloc((size_t)N * 4);
    int*      ghist  = (int*)alloc((size_t)nb * 4);
    int*      boff   = (int*)alloc((size_t)(nb + 1) * 4);
    int*      cursor = (int*)alloc((size_t)nb * 4);
    int*      rowptr = (int*)alloc((size_t)(N + 1) * 4);
    int*      rowmid = (int*)alloc((size_t)N * 4);
    unsigned* packed = (unsigned*)alloc((size_t)E * 4);
    int*      col    = (int*)alloc((size_t)E * 4);
    __half*   zA     = (__half*)alloc((size_t)N * 16 * 2);   // interleaved 32B/node
    __half*   zB     = (__half*)alloc((size_t)N * 16 * 2);
    float*    hp     = (float*)alloc((size_t)N * DIM * 4);
    float*    pp     = (float*)alloc((size_t)N * DIM * 4);   // lo-half partials
    float*    bnsum  = (float*)alloc((size_t)L * 256 * 4);   // 8 replicas x 32 per layer
    float*    ssbuf  = (float*)alloc((size_t)L * 32 * 4);

    hipMemsetAsync(ghist, 0, (size_t)nb * 4, stream);
    hipMemsetAsync(bnsum, 0, (size_t)L * 256 * 4, stream);

    const int nhist = (E + HIST_CHUNK - 1) / HIST_CHUNK;
    const int nbin  = (E + BIN_CHUNK - 1) / BIN_CHUNK;
    hist_kernel<<<nhist, 256, 0, stream>>>(dst, ghist, E, nb);
    scan_kernel<<<1, 256, 0, stream>>>(ghist, boff, cursor, nb, E);
    bin_kernel<<<nbin, 256, 0, stream>>>(src, dst, cursor, packed, E, nb);
    const size_t csr_lds = (size_t)(CSR_CAP + 4 * BUCK_SIZE) * 4;   // 149504 B
    csr_kernel<<<nb, 1024, csr_lds, stream>>>(packed, boff, rowptr, rowmid, dinv, col, N, E, NH);

    const int G = (N * 8 + 255) / 256;         // gather grid (8 lanes/node)

    // layer 0: z0 then one two-pass identity-epilogue traversal
    z0_kernel<<<(N * 2 + 255) / 256, 256, 0, stream>>>(x, W_in, dinv, zA, N);
    gatherP_kernel<<<G, 256, 0, stream>>>(rowptr, rowmid, col, zA, pp, N);
    gatherE_kernel<0><<<G, 256, 0, stream>>>(rowptr, rowmid, col, zA, dinv, pp,
                                             nullptr, nullptr, b_in, nullptr,
                                             nullptr, nullptr, zB, nullptr, N);
    __half* cur = zB;
    __half* nxt = zA;

    for (int l = 0; l < L; ++l) {
        gatherP_kernel<<<G, 256, 0, stream>>>(rowptr, rowmid, col, cur, pp, N);
        gatherE_kernel<1><<<G, 256, 0, stream>>>(rowptr, rowmid, col, cur, dinv, pp,
                                                 Ws + l * DIM * DIM, nullptr,
                                                 bs + l * DIM, nullptr,
                                                 hp, nullptr, nullptr,
                                                 bnsum + l * 256, N);
        bnfin_kernel<<<1, 64, 0, stream>>>(bnsum + l * 256, gammas + l * DIM,
                                           betas + l * DIM, ssbuf + l * 32, N);
        bn_relu_z_kernel<<<(N * 2 + 255) / 256, 256, 0, stream>>>(hp, ssbuf + l * 32, dinv,
                                                                  nxt, N);
        __half* tz = cur; cur = nxt; nxt = tz;
    }

    // heads: two-pass traversal, dual epilogue into d_out
    gatherP_kernel<<<G, 256, 0, stream>>>(rowptr, rowmid, col, cur, pp, N);
    gatherE_kernel<3><<<G, 256, 0, stream>>>(rowptr, rowmid, col, cur, dinv, pp,
                                             W_sin, W_cos, b_sin, b_cos,
                                             out, out + (size_t)N * DIM, nullptr,
                                             nullptr, N);
}

// Round 9
// 794.724 us; speedup vs baseline: 1.0216x; 1.0216x over previous
//
#include <hip/hip_runtime.h>
#include <hip/hip_fp16.h>

// RNAGNN round 15: revert gathers to single-pass gatherF (round-13, 767 us —
// round-14 two-pass proved gather is NOT BW-bound: FETCH 244->51 MB but time
// regressed). This round attacks preprocessing slack: bin_kernel was 65 us at
// 20% occupancy (46 KB LDS). BIN_CHUNK 8192->4096 cuts staging to 25 KB ->
// 6 blocks/CU; LDS-sorted linear flush keeps writes run-coalesced (unlike the
// round-8 direct-scatter failure). gatherF col reads now nontemporal so the
// 25.6 MB/pass col stream doesn't evict z from L2.

#define DIM 16
#define F_IN 64
#define BUCK_SHIFT 10
#define BUCK_SIZE 1024
#define MAXB 256            // nb = ceil(200000/1024) = 196
#define HIST_CHUNK 4096
#define BIN_CHUNK 4096
#define EPB 16              // edges per thread in bin (4096/256)
#define CSR_CAP 33280       // staging words: mean 32653 + ~3.5 sigma; fallback beyond

// LDS weight layout: W[f][j] at f*17+j -> lanes with distinct f hit distinct banks
#define WA_OFF 0
#define WB_OFF 272
#define BA_OFF 544
#define BB_OFF 560
#define SW_SIZE 576
#define WIDX(f, j) ((f) * 17 + (j))

// ---------------- per-bucket edge histogram ----------------

__global__ void hist_kernel(const int* __restrict__ dst, int* __restrict__ ghist,
                            int E, int nb) {
    __shared__ int lh[MAXB];
    int t = threadIdx.x;
    for (int i = t; i < nb; i += 256) lh[i] = 0;
    __syncthreads();
    int base = blockIdx.x * HIST_CHUNK;
    int end = min(base + HIST_CHUNK, E);
    for (int e = base + t; e < end; e += 256) atomicAdd(&lh[dst[e] >> BUCK_SHIFT], 1);
    __syncthreads();
    for (int b = t; b < nb; b += 256) {
        int c = lh[b];
        if (c) atomicAdd(&ghist[b], c);
    }
}

// exclusive scan of ghist (nb <= 256) -> boff, cursor
__global__ void scan_kernel(const int* __restrict__ ghist, int* __restrict__ boff,
                            int* __restrict__ cursor, int nb, int E) {
    __shared__ int sd[256];
    int t = threadIdx.x;
    int v = (t < nb) ? ghist[t] : 0;
    sd[t] = v;
    __syncthreads();
    for (int off = 1; off < 256; off <<= 1) {
        int u = (t >= off) ? sd[t - off] : 0;
        __syncthreads();
        sd[t] += u;
        __syncthreads();
    }
    if (t < nb) {
        int excl = sd[t] - v;
        boff[t] = excl;
        cursor[t] = excl;
    }
    if (t == 255) boff[nb] = E;
}

// pass A: bin edges into dst-range buckets; packed = src | (local_dst << 18).
// LDS bucket-sort within the block, then linear (coalesced) flush to global.
// 25 KB LDS -> 6 blocks/CU (was 46 KB / 3 blocks at chunk 8192).
__launch_bounds__(256)
__global__ void bin_kernel(const int* __restrict__ src, const int* __restrict__ dst,
                           int* __restrict__ cursor, unsigned* __restrict__ packed,
                           int E, int nb) {
    __shared__ unsigned sedge[BIN_CHUNK];        // 16 KB sorted packed values
    __shared__ unsigned char sbid[BIN_CHUNK];    // 4 KB bucket id per slot
    __shared__ int lh[MAXB];
    __shared__ int sd[MAXB];
    __shared__ int lstart[MAXB];
    __shared__ int lrank[MAXB];
    __shared__ int gbase[MAXB];

    int t = threadIdx.x;
    int base = blockIdx.x * BIN_CHUNK;
    int end = min(base + BIN_CHUNK, E);
    lh[t] = 0;
    __syncthreads();

    unsigned pv[EPB];
    int bk[EPB];
#pragma unroll
    for (int i = 0; i < EPB; ++i) {
        int e = base + t + i * 256;
        if (e < end) {
            int d = dst[e];
            int b = d >> BUCK_SHIFT;
            pv[i] = (unsigned)src[e] | ((unsigned)(d & (BUCK_SIZE - 1)) << 18);
            bk[i] = b;
            atomicAdd(&lh[b], 1);
        } else {
            bk[i] = -1;
            pv[i] = 0u;
        }
    }
    __syncthreads();

    int v = (t < nb) ? lh[t] : 0;
    sd[t] = v;
    __syncthreads();
    for (int off = 1; off < 256; off <<= 1) {
        int u = (t >= off) ? sd[t - off] : 0;
        __syncthreads();
        sd[t] += u;
        __syncthreads();
    }
    if (t < nb) {
        lstart[t] = sd[t] - v;
        lrank[t] = 0;
        gbase[t] = v ? atomicAdd(&cursor[t], v) : 0;
    }
    __syncthreads();

#pragma unroll
    for (int i = 0; i < EPB; ++i) {
        int b = bk[i];
        if (b >= 0) {
            int rank = atomicAdd(&lrank[b], 1);
            int p = lstart[b] + rank;
            sedge[p] = pv[i];
            sbid[p] = (unsigned char)b;
        }
    }
    __syncthreads();

    int total = end - base;
    for (int j = t; j < total; j += 256) {
        int b = sbid[j];
        packed[(size_t)gbase[b] + (unsigned)(j - lstart[b])] = sedge[j];
    }
}

// pass B: bucket -> exact CSR via LDS staging (coalesced col writes).
// Dynamic LDS: sstage[CSR_CAP] (sd aliases it) + cnt[1024] + scur[1024].
__launch_bounds__(1024)
__global__ void csr_kernel(const unsigned* __restrict__ packed, const int* __restrict__ boff,
                           int* __restrict__ rowptr, float* __restrict__ dinv,
                           int* __restrict__ col, int N, int E) {
    extern __shared__ unsigned smem[];
    unsigned* sstage = smem;                 // CSR_CAP words (sd aliases first 1024)
    int* sd   = (int*)smem;
    int* cnt  = (int*)(smem + CSR_CAP);
    int* scur = cnt + BUCK_SIZE;

    int t = threadIdx.x, blk = blockIdx.x;
    cnt[t] = 0;
    __syncthreads();
    int b0 = boff[blk], e1 = boff[blk + 1];
    for (int e = b0 + t; e < e1; e += 1024) atomicAdd(&cnt[packed[e] >> 18], 1);
    __syncthreads();
    int d = cnt[t];
    sd[t] = d;
    __syncthreads();
    for (int off = 1; off < 1024; off <<= 1) {
        int v = (t >= off) ? sd[t - off] : 0;
        __syncthreads();
        sd[t] += v;
        __syncthreads();
    }
    int lstart = sd[t] - d;                  // 0-based within bucket
    int i = (blk << BUCK_SHIFT) + t;
    if (i < N) {
        rowptr[i] = b0 + lstart;
        dinv[i] = rsqrtf((float)(d + 1));    // +1 = self loop
        if (i == N - 1) rowptr[N] = E;
    }
    scur[t] = lstart;
    __syncthreads();                         // all done reading sd before staging overwrites
    for (int e = b0 + t; e < e1; e += 1024) {
        unsigned k = packed[e];
        int pos = atomicAdd(&scur[k >> 18], 1);
        unsigned val = k & 0x3FFFFu;
        if (pos < CSR_CAP) sstage[pos] = val;
        else col[(size_t)b0 + pos] = val;    // overflow fallback (rare)
    }
    __syncthreads();
    int total = e1 - b0;
    int lim = min(total, CSR_CAP);
    for (int j = t; j < lim; j += 1024) col[(size_t)b0 + j] = sstage[j];
}

// ---------------- z0 = dinv * (x @ W_in), interleaved 16-feat fp16 table ----------------

__global__ void z0_kernel(const float* __restrict__ x, const float* __restrict__ W,
                          const float* __restrict__ dinv,
                          __half* __restrict__ z, int n) {
    __shared__ float sW[F_IN * DIM];
    int t = threadIdx.x;
#pragma unroll
    for (int j = 0; j < 4; ++j) sW[t + j * 256] = W[t + j * 256];
    __syncthreads();
    int idx = blockIdx.x * 256 + t;
    if (idx >= n * 2) return;
    int node = idx >> 1, p = idx & 1;
    float acc[8] = {0, 0, 0, 0, 0, 0, 0, 0};
    const float4* xr = (const float4*)(x + (size_t)node * F_IN);
#pragma unroll
    for (int k4 = 0; k4 < 16; ++k4) {
        float4 xv = xr[k4];
        float c[4] = { xv.x, xv.y, xv.z, xv.w };
#pragma unroll
        for (int cc = 0; cc < 4; ++cc) {
            const float* wr = &sW[(k4 * 4 + cc) * DIM + p * 8];
#pragma unroll
            for (int j = 0; j < 8; ++j) acc[j] += c[cc] * wr[j];
        }
    }
    float di = dinv[node];
    __half2 o[4];
#pragma unroll
    for (int m = 0; m < 4; ++m) o[m] = __floats2half2_rn(di * acc[2 * m], di * acc[2 * m + 1]);
    *(float4*)(z + ((size_t)node << 4) + p * 8) = *(float4*)o;
}

// ---------------- fused gather: one traversal, full 16-feat rows ----------------
// MODE 0 : identity epilogue, znext = fp16(di*(r + b))          (layer 0)
// MODE 1 : matmul -> o1 (pre-BN fp32) + BN partials -> bnsum replica
// MODE 3 : dual matmul + ReLU -> o1, o2 (heads)

template <int MODE>
__launch_bounds__(256)
__global__ void gatherF_kernel(const int* __restrict__ rowptr, const int* __restrict__ col,
                               const __half* __restrict__ z, const float* __restrict__ dinv,
                               const float* __restrict__ Wa, const float* __restrict__ Wb,
                               const float* __restrict__ ba, const float* __restrict__ bb,
                               float* __restrict__ o1, float* __restrict__ o2,
                               __half* __restrict__ znext, float* __restrict__ bnsum, int N) {
    __shared__ float sW[SW_SIZE];
    __shared__ float sred[4][32];
    int t = threadIdx.x;
    if (MODE == 1 || MODE == 3) {
        int f = t >> 4, j = t & 15;
        sW[WA_OFF + WIDX(f, j)] = Wa[t];
        if (MODE == 3) sW[WB_OFF + WIDX(f, j)] = Wb[t];
        if (t < 16) {
            sW[BA_OFF + t] = ba[t];
            if (MODE == 3) sW[BB_OFF + t] = bb[t];
        }
        __syncthreads();
    } else {
        if (t < 16) sW[BA_OFF + t] = ba[t];
        __syncthreads();
    }

    int idx = blockIdx.x * 256 + t;
    int node = idx >> 3, o = idx & 7;          // 8 lanes per node
    bool alive = node < N;
    float a[16];
#pragma unroll
    for (int j = 0; j < 16; ++j) a[j] = 0.f;
    float di = 0.f;
    if (alive) {
        di = dinv[node];
        int start = rowptr[node];
        int len = rowptr[node + 1] - start;
        int k = o;
        for (; k + 8 < len; k += 16) {         // 2 edges in flight per lane
            int s0 = __builtin_nontemporal_load(col + start + k);
            int s1 = __builtin_nontemporal_load(col + start + k + 8);
            const float4* q0 = (const float4*)(z + ((size_t)s0 << 4));
            const float4* q1 = (const float4*)(z + ((size_t)s1 << 4));
            float4 v0l = q0[0], v0h = q0[1];
            float4 v1l = q1[0], v1h = q1[1];
            const __half2* h0l = (const __half2*)&v0l;
            const __half2* h0h = (const __half2*)&v0h;
            const __half2* h1l = (const __half2*)&v1l;
            const __half2* h1h = (const __half2*)&v1h;
#pragma unroll
            for (int m = 0; m < 4; ++m) {
                float2 f0 = __half22float2(h0l[m]);
                float2 f1 = __half22float2(h1l[m]);
                a[2 * m] += f0.x + f1.x;
                a[2 * m + 1] += f0.y + f1.y;
                float2 g0 = __half22float2(h0h[m]);
                float2 g1 = __half22float2(h1h[m]);
                a[8 + 2 * m] += g0.x + g1.x;
                a[8 + 2 * m + 1] += g0.y + g1.y;
            }
        }
        if (k < len) {
            int s = __builtin_nontemporal_load(col + start + k);
            const float4* q = (const float4*)(z + ((size_t)s << 4));
            float4 vl = q[0], vh = q[1];
            const __half2* hl = (const __half2*)&vl;
            const __half2* hh = (const __half2*)&vh;
#pragma unroll
            for (int m = 0; m < 4; ++m) {
                float2 f2 = __half22float2(hl[m]);
                a[2 * m] += f2.x; a[2 * m + 1] += f2.y;
                float2 g2 = __half22float2(hh[m]);
                a[8 + 2 * m] += g2.x; a[8 + 2 * m + 1] += g2.y;
            }
        }
    }
#pragma unroll
    for (int j = 0; j < 16; ++j) {
        a[j] += __shfl_xor(a[j], 1);
        a[j] += __shfl_xor(a[j], 2);
        a[j] += __shfl_xor(a[j], 4);
    }
    if (alive) {   // self loop (all 8 lanes add same value -> consistent)
        const float4* q = (const float4*)(z + ((size_t)node << 4));
        float4 vl = q[0], vh = q[1];
        const __half2* hl = (const __half2*)&vl;
        const __half2* hh = (const __half2*)&vh;
#pragma unroll
        for (int m = 0; m < 4; ++m) {
            float2 f2 = __half22float2(hl[m]);
            a[2 * m] += f2.x; a[2 * m + 1] += f2.y;
            float2 g2 = __half22float2(hh[m]);
            a[8 + 2 * m] += g2.x; a[8 + 2 * m + 1] += g2.y;
        }
    }
    float r[16];
#pragma unroll
    for (int j = 0; j < 16; ++j) r[j] = di * a[j];

    if (MODE == 0) {
        if (alive && o == 0) {
            __half2 ov[8];
#pragma unroll
            for (int m = 0; m < 8; ++m)
                ov[m] = __floats2half2_rn(di * (r[2 * m] + sW[BA_OFF + 2 * m]),
                                          di * (r[2 * m + 1] + sW[BA_OFF + 2 * m + 1]));
            *(float4*)(znext + ((size_t)node << 4)) = ((float4*)ov)[0];
            *(float4*)(znext + ((size_t)node << 4) + 8) = ((float4*)ov)[1];
        }
        return;
    }

    // MODE 1 / 3: lane o owns input feats {2o, 2o+1} (lane-local, select to
    // avoid runtime-indexed array -> scratch)
    float rc0 = 0.f, rc1 = 0.f;
#pragma unroll
    for (int j = 0; j < 8; ++j)
        if (o == j) { rc0 = r[2 * j]; rc1 = r[2 * j + 1]; }
    if (!alive) { rc0 = 0.f; rc1 = 0.f; }
    int f0 = 2 * o;
    float pa[16];
#pragma unroll
    for (int j = 0; j < 16; ++j)
        pa[j] = rc0 * sW[WA_OFF + WIDX(f0, j)] + rc1 * sW[WA_OFF + WIDX(f0 + 1, j)];
#pragma unroll
    for (int j = 0; j < 16; ++j) {
        pa[j] += __shfl_xor(pa[j], 1);
        pa[j] += __shfl_xor(pa[j], 2);
        pa[j] += __shfl_xor(pa[j], 4);
    }

    if (MODE == 1) {
        float o0 = 0.f, o1v = 0.f;
#pragma unroll
        for (int j = 0; j < 8; ++j)
            if (o == j) {
                o0 = pa[2 * j] + sW[BA_OFF + 2 * j];
                o1v = pa[2 * j + 1] + sW[BA_OFF + 2 * j + 1];
            }
        if (alive)
            *(float2*)(o1 + ((size_t)node << 4) + 2 * o) = make_float2(o0, o1v);
        float s0 = alive ? o0 : 0.f, s1 = alive ? o1v : 0.f;
        float q0 = s0 * s0, q1 = s1 * s1;
#pragma unroll
        for (int m = 8; m <= 32; m <<= 1) {
            s0 += __shfl_xor(s0, m); s1 += __shfl_xor(s1, m);
            q0 += __shfl_xor(q0, m); q1 += __shfl_xor(q1, m);
        }
        int lane = t & 63, wave = t >> 6;
        if (lane < 8) {
            sred[wave][2 * lane] = s0;
            sred[wave][2 * lane + 1] = s1;
            sred[wave][16 + 2 * lane] = q0;
            sred[wave][16 + 2 * lane + 1] = q1;
        }
        __syncthreads();
        if (t < 32) {
            float v = sred[0][t] + sred[1][t] + sred[2][t] + sred[3][t];
            atomicAdd(&bnsum[(blockIdx.x & 7) * 32 + t], v);
        }
        return;
    }

    // MODE 3: dual heads
    {
        float pb[16];
#pragma unroll
        for (int j = 0; j < 16; ++j)
            pb[j] = rc0 * sW[WB_OFF + WIDX(f0, j)] + rc1 * sW[WB_OFF + WIDX(f0 + 1, j)];
#pragma unroll
        for (int j = 0; j < 16; ++j) {
            pb[j] += __shfl_xor(pb[j], 1);
            pb[j] += __shfl_xor(pb[j], 2);
            pb[j] += __shfl_xor(pb[j], 4);
        }
        if (alive) {
            float oa0 = 0.f, oa1 = 0.f, ob0 = 0.f, ob1 = 0.f;
#pragma unroll
            for (int j = 0; j < 8; ++j)
                if (o == j) {
                    oa0 = fmaxf(pa[2 * j] + sW[BA_OFF + 2 * j], 0.f);
                    oa1 = fmaxf(pa[2 * j + 1] + sW[BA_OFF + 2 * j + 1], 0.f);
                    ob0 = fmaxf(pb[2 * j] + sW[BB_OFF + 2 * j], 0.f);
                    ob1 = fmaxf(pb[2 * j + 1] + sW[BB_OFF + 2 * j + 1], 0.f);
                }
            *(float2*)(o1 + ((size_t)node << 4) + 2 * o) = make_float2(oa0, oa1);
            *(float2*)(o2 + ((size_t)node << 4) + 2 * o) = make_float2(ob0, ob1);
        }
    }
}

// ---------------- BN finalize (8 replicas -> scale/shift) ----------------

__global__ void bnfin_kernel(const float* __restrict__ bnsum, const float* __restrict__ gamma,
                             const float* __restrict__ beta, float* __restrict__ ssout, int n) {
    int t = threadIdx.x;
    if (t >= 16) return;
    float s = 0.f, sq = 0.f;
#pragma unroll
    for (int rep = 0; rep < 8; ++rep) {
        s += bnsum[rep * 32 + t];
        sq += bnsum[rep * 32 + 16 + t];
    }
    float invN = 1.f / (float)n;
    float mean = s * invN;
    float var = fmaxf(sq * invN - mean * mean, 0.f);
    float scale = gamma[t] * rsqrtf(var + 1e-5f);
    ssout[t] = scale;
    ssout[16 + t] = beta[t] - mean * scale;
}

// ---------------- BN apply + ReLU -> next interleaved z table ----------------

__global__ void bn_relu_z_kernel(const float* __restrict__ hp, const float* __restrict__ ss,
                                 const float* __restrict__ dinv,
                                 __half* __restrict__ z, int n) {
    int idx = blockIdx.x * 256 + threadIdx.x;
    if (idx >= n * 2) return;
    int node = idx >> 1, p = idx & 1;
    float di = dinv[node];
    const float4* hr = (const float4*)(hp + ((size_t)node << 4) + p * 8);
    float4 v0 = hr[0], v1 = hr[1];
    float vv[8] = { v0.x, v0.y, v0.z, v0.w, v1.x, v1.y, v1.z, v1.w };
    __half2 o[4];
#pragma unroll
    for (int m = 0; m < 4; ++m) {
        int f0 = p * 8 + 2 * m;
        float r0 = di * fmaxf(vv[2 * m] * ss[f0] + ss[16 + f0], 0.f);
        float r1 = di * fmaxf(vv[2 * m + 1] * ss[f0 + 1] + ss[16 + f0 + 1], 0.f);
        o[m] = __floats2half2_rn(r0, r1);
    }
    *(float4*)(z + ((size_t)node << 4) + p * 8) = *(float4*)o;
}

// ---------------- launcher ----------------

extern "C" void kernel_launch(void* const* d_in, const int* in_sizes, int n_in,
                              void* d_out, int out_size, void* d_ws, size_t ws_size,
                              hipStream_t stream) {
    (void)n_in; (void)out_size; (void)ws_size;
    const float* x      = (const float*)d_in[0];
    const int*   edge   = (const int*)d_in[1];
    const float* W_in   = (const float*)d_in[2];
    const float* b_in   = (const float*)d_in[3];
    const float* Ws     = (const float*)d_in[4];
    const float* bs     = (const float*)d_in[5];
    const float* gammas = (const float*)d_in[6];
    const float* betas  = (const float*)d_in[7];
    const float* W_sin  = (const float*)d_in[8];
    const float* b_sin  = (const float*)d_in[9];
    const float* W_cos  = (const float*)d_in[10];
    const float* b_cos  = (const float*)d_in[11];
    float* out = (float*)d_out;

    const int N = in_sizes[0] / F_IN;          // 200000
    const int E = in_sizes[1] / 2;             // 6400000
    const int L = in_sizes[4] / (DIM * DIM);   // 4
    const int nb = (N + BUCK_SIZE - 1) >> BUCK_SHIFT;   // 196
    const int* src = edge;
    const int* dst = edge + E;

    char* ws = (char*)d_ws;
    size_t off = 0;
    auto alloc = [&](size_t bytes) { char* p = ws + off; off += (bytes + 15) & ~size_t(15); return p; };
    float*    dinv   = (float*)alloc((size_t)N * 4);
    int*      ghist  = (int*)alloc((size_t)nb * 4);
    int*      boff   = (int*)alloc((size_t)(nb + 1) * 4);
    int*      cursor = (int*)alloc((size_t)nb * 4);
    int*      rowptr = (int*)alloc((size_t)(N + 1) * 4);
    unsigned* packed = (unsigned*)alloc((size_t)E * 4);
    int*      col    = (int*)alloc((size_t)E * 4);
    __half*   zA     = (__half*)alloc((size_t)N * 16 * 2);   // interleaved 32B/node
    __half*   zB     = (__half*)alloc((size_t)N * 16 * 2);
    float*    hp     = (float*)alloc((size_t)N * DIM * 4);
    float*    bnsum  = (float*)alloc((size_t)L * 256 * 4);   // 8 replicas x 32 per layer
    float*    ssbuf  = (float*)alloc((size_t)L * 32 * 4);

    hipMemsetAsync(ghist, 0, (size_t)nb * 4, stream);
    hipMemsetAsync(bnsum, 0, (size_t)L * 256 * 4, stream);

    const int nhist = (E + HIST_CHUNK - 1) / HIST_CHUNK;
    const int nbin  = (E + BIN_CHUNK - 1) / BIN_CHUNK;
    hist_kernel<<<nhist, 256, 0, stream>>>(dst, ghist, E, nb);
    scan_kernel<<<1, 256, 0, stream>>>(ghist, boff, cursor, nb, E);
    bin_kernel<<<nbin, 256, 0, stream>>>(src, dst, cursor, packed, E, nb);
    const size_t csr_lds = (size_t)(CSR_CAP + 2 * BUCK_SIZE) * 4;   // 141312 B
    csr_kernel<<<nb, 1024, csr_lds, stream>>>(packed, boff, rowptr, dinv, col, N, E);

    const int G = (N * 8 + 255) / 256;         // gather grid (8 lanes/node)

    // layer 0: z0 then one fused identity-epilogue traversal
    z0_kernel<<<(N * 2 + 255) / 256, 256, 0, stream>>>(x, W_in, dinv, zA, N);
    gatherF_kernel<0><<<G, 256, 0, stream>>>(rowptr, col, zA, dinv,
                                             nullptr, nullptr, b_in, nullptr,
                                             nullptr, nullptr, zB, nullptr, N);
    __half* cur = zB;
    __half* nxt = zA;

    for (int l = 0; l < L; ++l) {
        gatherF_kernel<1><<<G, 256, 0, stream>>>(rowptr, col, cur, dinv,
                                                 Ws + l * DIM * DIM, nullptr,
                                                 bs + l * DIM, nullptr,
                                                 hp, nullptr, nullptr,
                                                 bnsum + l * 256, N);
        bnfin_kernel<<<1, 64, 0, stream>>>(bnsum + l * 256, gammas + l * DIM,
                                           betas + l * DIM, ssbuf + l * 32, N);
        bn_relu_z_kernel<<<(N * 2 + 255) / 256, 256, 0, stream>>>(hp, ssbuf + l * 32, dinv,
                                                                  nxt, N);
        __half* tz = cur; cur = nxt; nxt = tz;
    }

    // heads: one traversal, dual epilogue into d_out
    gatherF_kernel<3><<<G, 256, 0, stream>>>(rowptr, col, cur, dinv,
                                             W_sin, W_cos, b_sin, b_cos,
                                             out, out + (size_t)N * DIM, nullptr,
                                             nullptr, N);
}

// Round 10
// 779.750 us; speedup vs baseline: 1.0413x; 1.0192x over previous
//
#include <hip/hip_runtime.h>
#include <hip/hip_fp16.h>

// RNAGNN round 16: (1) REVERT nontemporal col loads (round-15 regression:
// nt bypasses L2 -> full HBM latency on the col stream, gather 83->89 us).
// (2) 4-deep z-load pipeline per lane (k,k+8,k+16,k+24; all 8 float4 loads
// issued before accumulation) — gather is latency-bound (round-14: FETCH
// 244->51MB didn't help), so double the per-lane MLP. Keep BIN_CHUNK 4096
// (bin left top-5 in round 15).

#define DIM 16
#define F_IN 64
#define BUCK_SHIFT 10
#define BUCK_SIZE 1024
#define MAXB 256            // nb = ceil(200000/1024) = 196
#define HIST_CHUNK 4096
#define BIN_CHUNK 4096
#define EPB 16              // edges per thread in bin (4096/256)
#define CSR_CAP 33280       // staging words: mean 32653 + ~3.5 sigma; fallback beyond

// LDS weight layout: W[f][j] at f*17+j -> lanes with distinct f hit distinct banks
#define WA_OFF 0
#define WB_OFF 272
#define BA_OFF 544
#define BB_OFF 560
#define SW_SIZE 576
#define WIDX(f, j) ((f) * 17 + (j))

// ---------------- per-bucket edge histogram ----------------

__global__ void hist_kernel(const int* __restrict__ dst, int* __restrict__ ghist,
                            int E, int nb) {
    __shared__ int lh[MAXB];
    int t = threadIdx.x;
    for (int i = t; i < nb; i += 256) lh[i] = 0;
    __syncthreads();
    int base = blockIdx.x * HIST_CHUNK;
    int end = min(base + HIST_CHUNK, E);
    for (int e = base + t; e < end; e += 256) atomicAdd(&lh[dst[e] >> BUCK_SHIFT], 1);
    __syncthreads();
    for (int b = t; b < nb; b += 256) {
        int c = lh[b];
        if (c) atomicAdd(&ghist[b], c);
    }
}

// exclusive scan of ghist (nb <= 256) -> boff, cursor
__global__ void scan_kernel(const int* __restrict__ ghist, int* __restrict__ boff,
                            int* __restrict__ cursor, int nb, int E) {
    __shared__ int sd[256];
    int t = threadIdx.x;
    int v = (t < nb) ? ghist[t] : 0;
    sd[t] = v;
    __syncthreads();
    for (int off = 1; off < 256; off <<= 1) {
        int u = (t >= off) ? sd[t - off] : 0;
        __syncthreads();
        sd[t] += u;
        __syncthreads();
    }
    if (t < nb) {
        int excl = sd[t] - v;
        boff[t] = excl;
        cursor[t] = excl;
    }
    if (t == 255) boff[nb] = E;
}

// pass A: bin edges into dst-range buckets; packed = src | (local_dst << 18).
// LDS bucket-sort within the block, then linear (coalesced) flush to global.
__launch_bounds__(256)
__global__ void bin_kernel(const int* __restrict__ src, const int* __restrict__ dst,
                           int* __restrict__ cursor, unsigned* __restrict__ packed,
                           int E, int nb) {
    __shared__ unsigned sedge[BIN_CHUNK];        // 16 KB sorted packed values
    __shared__ unsigned char sbid[BIN_CHUNK];    // 4 KB bucket id per slot
    __shared__ int lh[MAXB];
    __shared__ int sd[MAXB];
    __shared__ int lstart[MAXB];
    __shared__ int lrank[MAXB];
    __shared__ int gbase[MAXB];

    int t = threadIdx.x;
    int base = blockIdx.x * BIN_CHUNK;
    int end = min(base + BIN_CHUNK, E);
    lh[t] = 0;
    __syncthreads();

    unsigned pv[EPB];
    int bk[EPB];
#pragma unroll
    for (int i = 0; i < EPB; ++i) {
        int e = base + t + i * 256;
        if (e < end) {
            int d = dst[e];
            int b = d >> BUCK_SHIFT;
            pv[i] = (unsigned)src[e] | ((unsigned)(d & (BUCK_SIZE - 1)) << 18);
            bk[i] = b;
            atomicAdd(&lh[b], 1);
        } else {
            bk[i] = -1;
            pv[i] = 0u;
        }
    }
    __syncthreads();

    int v = (t < nb) ? lh[t] : 0;
    sd[t] = v;
    __syncthreads();
    for (int off = 1; off < 256; off <<= 1) {
        int u = (t >= off) ? sd[t - off] : 0;
        __syncthreads();
        sd[t] += u;
        __syncthreads();
    }
    if (t < nb) {
        lstart[t] = sd[t] - v;
        lrank[t] = 0;
        gbase[t] = v ? atomicAdd(&cursor[t], v) : 0;
    }
    __syncthreads();

#pragma unroll
    for (int i = 0; i < EPB; ++i) {
        int b = bk[i];
        if (b >= 0) {
            int rank = atomicAdd(&lrank[b], 1);
            int p = lstart[b] + rank;
            sedge[p] = pv[i];
            sbid[p] = (unsigned char)b;
        }
    }
    __syncthreads();

    int total = end - base;
    for (int j = t; j < total; j += 256) {
        int b = sbid[j];
        packed[(size_t)gbase[b] + (unsigned)(j - lstart[b])] = sedge[j];
    }
}

// pass B: bucket -> exact CSR via LDS staging (coalesced col writes).
// Dynamic LDS: sstage[CSR_CAP] (sd aliases it) + cnt[1024] + scur[1024].
__launch_bounds__(1024)
__global__ void csr_kernel(const unsigned* __restrict__ packed, const int* __restrict__ boff,
                           int* __restrict__ rowptr, float* __restrict__ dinv,
                           int* __restrict__ col, int N, int E) {
    extern __shared__ unsigned smem[];
    unsigned* sstage = smem;                 // CSR_CAP words (sd aliases first 1024)
    int* sd   = (int*)smem;
    int* cnt  = (int*)(smem + CSR_CAP);
    int* scur = cnt + BUCK_SIZE;

    int t = threadIdx.x, blk = blockIdx.x;
    cnt[t] = 0;
    __syncthreads();
    int b0 = boff[blk], e1 = boff[blk + 1];
    for (int e = b0 + t; e < e1; e += 1024) atomicAdd(&cnt[packed[e] >> 18], 1);
    __syncthreads();
    int d = cnt[t];
    sd[t] = d;
    __syncthreads();
    for (int off = 1; off < 1024; off <<= 1) {
        int v = (t >= off) ? sd[t - off] : 0;
        __syncthreads();
        sd[t] += v;
        __syncthreads();
    }
    int lstart = sd[t] - d;                  // 0-based within bucket
    int i = (blk << BUCK_SHIFT) + t;
    if (i < N) {
        rowptr[i] = b0 + lstart;
        dinv[i] = rsqrtf((float)(d + 1));    // +1 = self loop
        if (i == N - 1) rowptr[N] = E;
    }
    scur[t] = lstart;
    __syncthreads();                         // all done reading sd before staging overwrites
    for (int e = b0 + t; e < e1; e += 1024) {
        unsigned k = packed[e];
        int pos = atomicAdd(&scur[k >> 18], 1);
        unsigned val = k & 0x3FFFFu;
        if (pos < CSR_CAP) sstage[pos] = val;
        else col[(size_t)b0 + pos] = val;    // overflow fallback (rare)
    }
    __syncthreads();
    int total = e1 - b0;
    int lim = min(total, CSR_CAP);
    for (int j = t; j < lim; j += 1024) col[(size_t)b0 + j] = sstage[j];
}

// ---------------- z0 = dinv * (x @ W_in), interleaved 16-feat fp16 table ----------------

__global__ void z0_kernel(const float* __restrict__ x, const float* __restrict__ W,
                          const float* __restrict__ dinv,
                          __half* __restrict__ z, int n) {
    __shared__ float sW[F_IN * DIM];
    int t = threadIdx.x;
#pragma unroll
    for (int j = 0; j < 4; ++j) sW[t + j * 256] = W[t + j * 256];
    __syncthreads();
    int idx = blockIdx.x * 256 + t;
    if (idx >= n * 2) return;
    int node = idx >> 1, p = idx & 1;
    float acc[8] = {0, 0, 0, 0, 0, 0, 0, 0};
    const float4* xr = (const float4*)(x + (size_t)node * F_IN);
#pragma unroll
    for (int k4 = 0; k4 < 16; ++k4) {
        float4 xv = xr[k4];
        float c[4] = { xv.x, xv.y, xv.z, xv.w };
#pragma unroll
        for (int cc = 0; cc < 4; ++cc) {
            const float* wr = &sW[(k4 * 4 + cc) * DIM + p * 8];
#pragma unroll
            for (int j = 0; j < 8; ++j) acc[j] += c[cc] * wr[j];
        }
    }
    float di = dinv[node];
    __half2 o[4];
#pragma unroll
    for (int m = 0; m < 4; ++m) o[m] = __floats2half2_rn(di * acc[2 * m], di * acc[2 * m + 1]);
    *(float4*)(z + ((size_t)node << 4) + p * 8) = *(float4*)o;
}

// accumulate one 32B z row (2 x float4, already loaded) into a[16]
#define ACC_ROW(vl, vh)                                                        \
    {                                                                          \
        const __half2* hl_ = (const __half2*)&(vl);                            \
        const __half2* hh_ = (const __half2*)&(vh);                            \
        _Pragma("unroll")                                                      \
        for (int m_ = 0; m_ < 4; ++m_) {                                       \
            float2 f2_ = __half22float2(hl_[m_]);                              \
            a[2 * m_] += f2_.x; a[2 * m_ + 1] += f2_.y;                        \
            float2 g2_ = __half22float2(hh_[m_]);                              \
            a[8 + 2 * m_] += g2_.x; a[8 + 2 * m_ + 1] += g2_.y;                \
        }                                                                      \
    }

// ---------------- fused gather: one traversal, full 16-feat rows ----------------
// MODE 0 : identity epilogue, znext = fp16(di*(r + b))          (layer 0)
// MODE 1 : matmul -> o1 (pre-BN fp32) + BN partials -> bnsum replica
// MODE 3 : dual matmul + ReLU -> o1, o2 (heads)

template <int MODE>
__launch_bounds__(256)
__global__ void gatherF_kernel(const int* __restrict__ rowptr, const int* __restrict__ col,
                               const __half* __restrict__ z, const float* __restrict__ dinv,
                               const float* __restrict__ Wa, const float* __restrict__ Wb,
                               const float* __restrict__ ba, const float* __restrict__ bb,
                               float* __restrict__ o1, float* __restrict__ o2,
                               __half* __restrict__ znext, float* __restrict__ bnsum, int N) {
    __shared__ float sW[SW_SIZE];
    __shared__ float sred[4][32];
    int t = threadIdx.x;
    if (MODE == 1 || MODE == 3) {
        int f = t >> 4, j = t & 15;
        sW[WA_OFF + WIDX(f, j)] = Wa[t];
        if (MODE == 3) sW[WB_OFF + WIDX(f, j)] = Wb[t];
        if (t < 16) {
            sW[BA_OFF + t] = ba[t];
            if (MODE == 3) sW[BB_OFF + t] = bb[t];
        }
        __syncthreads();
    } else {
        if (t < 16) sW[BA_OFF + t] = ba[t];
        __syncthreads();
    }

    int idx = blockIdx.x * 256 + t;
    int node = idx >> 3, o = idx & 7;          // 8 lanes per node
    bool alive = node < N;
    float a[16];
#pragma unroll
    for (int j = 0; j < 16; ++j) a[j] = 0.f;
    float di = 0.f;
    if (alive) {
        di = dinv[node];
        int start = rowptr[node];
        int len = rowptr[node + 1] - start;
        int k = o;
        // 4 edges in flight per lane: issue all 8 z-loads before accumulating
        for (; k + 24 < len; k += 32) {
            int s0 = col[start + k];
            int s1 = col[start + k + 8];
            int s2 = col[start + k + 16];
            int s3 = col[start + k + 24];
            const float4* q0 = (const float4*)(z + ((size_t)s0 << 4));
            const float4* q1 = (const float4*)(z + ((size_t)s1 << 4));
            const float4* q2 = (const float4*)(z + ((size_t)s2 << 4));
            const float4* q3 = (const float4*)(z + ((size_t)s3 << 4));
            float4 v0l = q0[0], v0h = q0[1];
            float4 v1l = q1[0], v1h = q1[1];
            float4 v2l = q2[0], v2h = q2[1];
            float4 v3l = q3[0], v3h = q3[1];
            ACC_ROW(v0l, v0h)
            ACC_ROW(v1l, v1h)
            ACC_ROW(v2l, v2h)
            ACC_ROW(v3l, v3h)
        }
        if (k + 8 < len) {                     // 2-deep tail
            int s0 = col[start + k];
            int s1 = col[start + k + 8];
            const float4* q0 = (const float4*)(z + ((size_t)s0 << 4));
            const float4* q1 = (const float4*)(z + ((size_t)s1 << 4));
            float4 v0l = q0[0], v0h = q0[1];
            float4 v1l = q1[0], v1h = q1[1];
            ACC_ROW(v0l, v0h)
            ACC_ROW(v1l, v1h)
            k += 16;
        }
        if (k < len) {                         // 1-deep tail
            int s = col[start + k];
            const float4* q = (const float4*)(z + ((size_t)s << 4));
            float4 vl = q[0], vh = q[1];
            ACC_ROW(vl, vh)
        }
    }
#pragma unroll
    for (int j = 0; j < 16; ++j) {
        a[j] += __shfl_xor(a[j], 1);
        a[j] += __shfl_xor(a[j], 2);
        a[j] += __shfl_xor(a[j], 4);
    }
    if (alive) {   // self loop (all 8 lanes add same value -> consistent)
        const float4* q = (const float4*)(z + ((size_t)node << 4));
        float4 vl = q[0], vh = q[1];
        ACC_ROW(vl, vh)
    }
    float r[16];
#pragma unroll
    for (int j = 0; j < 16; ++j) r[j] = di * a[j];

    if (MODE == 0) {
        if (alive && o == 0) {
            __half2 ov[8];
#pragma unroll
            for (int m = 0; m < 8; ++m)
                ov[m] = __floats2half2_rn(di * (r[2 * m] + sW[BA_OFF + 2 * m]),
                                          di * (r[2 * m + 1] + sW[BA_OFF + 2 * m + 1]));
            *(float4*)(znext + ((size_t)node << 4)) = ((float4*)ov)[0];
            *(float4*)(znext + ((size_t)node << 4) + 8) = ((float4*)ov)[1];
        }
        return;
    }

    // MODE 1 / 3: lane o owns input feats {2o, 2o+1} (lane-local, select to
    // avoid runtime-indexed array -> scratch)
    float rc0 = 0.f, rc1 = 0.f;
#pragma unroll
    for (int j = 0; j < 8; ++j)
        if (o == j) { rc0 = r[2 * j]; rc1 = r[2 * j + 1]; }
    if (!alive) { rc0 = 0.f; rc1 = 0.f; }
    int f0 = 2 * o;
    float pa[16];
#pragma unroll
    for (int j = 0; j < 16; ++j)
        pa[j] = rc0 * sW[WA_OFF + WIDX(f0, j)] + rc1 * sW[WA_OFF + WIDX(f0 + 1, j)];
#pragma unroll
    for (int j = 0; j < 16; ++j) {
        pa[j] += __shfl_xor(pa[j], 1);
        pa[j] += __shfl_xor(pa[j], 2);
        pa[j] += __shfl_xor(pa[j], 4);
    }

    if (MODE == 1) {
        float o0 = 0.f, o1v = 0.f;
#pragma unroll
        for (int j = 0; j < 8; ++j)
            if (o == j) {
                o0 = pa[2 * j] + sW[BA_OFF + 2 * j];
                o1v = pa[2 * j + 1] + sW[BA_OFF + 2 * j + 1];
            }
        if (alive)
            *(float2*)(o1 + ((size_t)node << 4) + 2 * o) = make_float2(o0, o1v);
        float s0 = alive ? o0 : 0.f, s1 = alive ? o1v : 0.f;
        float q0 = s0 * s0, q1 = s1 * s1;
#pragma unroll
        for (int m = 8; m <= 32; m <<= 1) {
            s0 += __shfl_xor(s0, m); s1 += __shfl_xor(s1, m);
            q0 += __shfl_xor(q0, m); q1 += __shfl_xor(q1, m);
        }
        int lane = t & 63, wave = t >> 6;
        if (lane < 8) {
            sred[wave][2 * lane] = s0;
            sred[wave][2 * lane + 1] = s1;
            sred[wave][16 + 2 * lane] = q0;
            sred[wave][16 + 2 * lane + 1] = q1;
        }
        __syncthreads();
        if (t < 32) {
            float v = sred[0][t] + sred[1][t] + sred[2][t] + sred[3][t];
            atomicAdd(&bnsum[(blockIdx.x & 7) * 32 + t], v);
        }
        return;
    }

    // MODE 3: dual heads
    {
        float pb[16];
#pragma unroll
        for (int j = 0; j < 16; ++j)
            pb[j] = rc0 * sW[WB_OFF + WIDX(f0, j)] + rc1 * sW[WB_OFF + WIDX(f0 + 1, j)];
#pragma unroll
        for (int j = 0; j < 16; ++j) {
            pb[j] += __shfl_xor(pb[j], 1);
            pb[j] += __shfl_xor(pb[j], 2);
            pb[j] += __shfl_xor(pb[j], 4);
        }
        if (alive) {
            float oa0 = 0.f, oa1 = 0.f, ob0 = 0.f, ob1 = 0.f;
#pragma unroll
            for (int j = 0; j < 8; ++j)
                if (o == j) {
                    oa0 = fmaxf(pa[2 * j] + sW[BA_OFF + 2 * j], 0.f);
                    oa1 = fmaxf(pa[2 * j + 1] + sW[BA_OFF + 2 * j + 1], 0.f);
                    ob0 = fmaxf(pb[2 * j] + sW[BB_OFF + 2 * j], 0.f);
                    ob1 = fmaxf(pb[2 * j + 1] + sW[BB_OFF + 2 * j + 1], 0.f);
                }
            *(float2*)(o1 + ((size_t)node << 4) + 2 * o) = make_float2(oa0, oa1);
            *(float2*)(o2 + ((size_t)node << 4) + 2 * o) = make_float2(ob0, ob1);
        }
    }
}

// ---------------- BN finalize (8 replicas -> scale/shift) ----------------

__global__ void bnfin_kernel(const float* __restrict__ bnsum, const float* __restrict__ gamma,
                             const float* __restrict__ beta, float* __restrict__ ssout, int n) {
    int t = threadIdx.x;
    if (t >= 16) return;
    float s = 0.f, sq = 0.f;
#pragma unroll
    for (int rep = 0; rep < 8; ++rep) {
        s += bnsum[rep * 32 + t];
        sq += bnsum[rep * 32 + 16 + t];
    }
    float invN = 1.f / (float)n;
    float mean = s * invN;
    float var = fmaxf(sq * invN - mean * mean, 0.f);
    float scale = gamma[t] * rsqrtf(var + 1e-5f);
    ssout[t] = scale;
    ssout[16 + t] = beta[t] - mean * scale;
}

// ---------------- BN apply + ReLU -> next interleaved z table ----------------

__global__ void bn_relu_z_kernel(const float* __restrict__ hp, const float* __restrict__ ss,
                                 const float* __restrict__ dinv,
                                 __half* __restrict__ z, int n) {
    int idx = blockIdx.x * 256 + threadIdx.x;
    if (idx >= n * 2) return;
    int node = idx >> 1, p = idx & 1;
    float di = dinv[node];
    const float4* hr = (const float4*)(hp + ((size_t)node << 4) + p * 8);
    float4 v0 = hr[0], v1 = hr[1];
    float vv[8] = { v0.x, v0.y, v0.z, v0.w, v1.x, v1.y, v1.z, v1.w };
    __half2 o[4];
#pragma unroll
    for (int m = 0; m < 4; ++m) {
        int f0 = p * 8 + 2 * m;
        float r0 = di * fmaxf(vv[2 * m] * ss[f0] + ss[16 + f0], 0.f);
        float r1 = di * fmaxf(vv[2 * m + 1] * ss[f0 + 1] + ss[16 + f0 + 1], 0.f);
        o[m] = __floats2half2_rn(r0, r1);
    }
    *(float4*)(z + ((size_t)node << 4) + p * 8) = *(float4*)o;
}

// ---------------- launcher ----------------

extern "C" void kernel_launch(void* const* d_in, const int* in_sizes, int n_in,
                              void* d_out, int out_size, void* d_ws, size_t ws_size,
                              hipStream_t stream) {
    (void)n_in; (void)out_size; (void)ws_size;
    const float* x      = (const float*)d_in[0];
    const int*   edge   = (const int*)d_in[1];
    const float* W_in   = (const float*)d_in[2];
    const float* b_in   = (const float*)d_in[3];
    const float* Ws     = (const float*)d_in[4];
    const float* bs     = (const float*)d_in[5];
    const float* gammas = (const float*)d_in[6];
    const float* betas  = (const float*)d_in[7];
    const float* W_sin  = (const float*)d_in[8];
    const float* b_sin  = (const float*)d_in[9];
    const float* W_cos  = (const float*)d_in[10];
    const float* b_cos  = (const float*)d_in[11];
    float* out = (float*)d_out;

    const int N = in_sizes[0] / F_IN;          // 200000
    const int E = in_sizes[1] / 2;             // 6400000
    const int L = in_sizes[4] / (DIM * DIM);   // 4
    const int nb = (N + BUCK_SIZE - 1) >> BUCK_SHIFT;   // 196
    const int* src = edge;
    const int* dst = edge + E;

    char* ws = (char*)d_ws;
    size_t off = 0;
    auto alloc = [&](size_t bytes) { char* p = ws + off; off += (bytes + 15) & ~size_t(15); return p; };
    float*    dinv   = (float*)alloc((size_t)N * 4);
    int*      ghist  = (int*)alloc((size_t)nb * 4);
    int*      boff   = (int*)alloc((size_t)(nb + 1) * 4);
    int*      cursor = (int*)alloc((size_t)nb * 4);
    int*      rowptr = (int*)alloc((size_t)(N + 1) * 4);
    unsigned* packed = (unsigned*)alloc((size_t)E * 4);
    int*      col    = (int*)alloc((size_t)E * 4);
    __half*   zA     = (__half*)alloc((size_t)N * 16 * 2);   // interleaved 32B/node
    __half*   zB     = (__half*)alloc((size_t)N * 16 * 2);
    float*    hp     = (float*)alloc((size_t)N * DIM * 4);
    float*    bnsum  = (float*)alloc((size_t)L * 256 * 4);   // 8 replicas x 32 per layer
    float*    ssbuf  = (float*)alloc((size_t)L * 32 * 4);

    hipMemsetAsync(ghist, 0, (size_t)nb * 4, stream);
    hipMemsetAsync(bnsum, 0, (size_t)L * 256 * 4, stream);

    const int nhist = (E + HIST_CHUNK - 1) / HIST_CHUNK;
    const int nbin  = (E + BIN_CHUNK - 1) / BIN_CHUNK;
    hist_kernel<<<nhist, 256, 0, stream>>>(dst, ghist, E, nb);
    scan_kernel<<<1, 256, 0, stream>>>(ghist, boff, cursor, nb, E);
    bin_kernel<<<nbin, 256, 0, stream>>>(src, dst, cursor, packed, E, nb);
    const size_t csr_lds = (size_t)(CSR_CAP + 2 * BUCK_SIZE) * 4;   // 141312 B
    csr_kernel<<<nb, 1024, csr_lds, stream>>>(packed, boff, rowptr, dinv, col, N, E);

    const int G = (N * 8 + 255) / 256;         // gather grid (8 lanes/node)

    // layer 0: z0 then one fused identity-epilogue traversal
    z0_kernel<<<(N * 2 + 255) / 256, 256, 0, stream>>>(x, W_in, dinv, zA, N);
    gatherF_kernel<0><<<G, 256, 0, stream>>>(rowptr, col, zA, dinv,
                                             nullptr, nullptr, b_in, nullptr,
                                             nullptr, nullptr, zB, nullptr, N);
    __half* cur = zB;
    __half* nxt = zA;

    for (int l = 0; l < L; ++l) {
        gatherF_kernel<1><<<G, 256, 0, stream>>>(rowptr, col, cur, dinv,
                                                 Ws + l * DIM * DIM, nullptr,
                                                 bs + l * DIM, nullptr,
                                                 hp, nullptr, nullptr,
                                                 bnsum + l * 256, N);
        bnfin_kernel<<<1, 64, 0, stream>>>(bnsum + l * 256, gammas + l * DIM,
                                           betas + l * DIM, ssbuf + l * 32, N);
        bn_relu_z_kernel<<<(N * 2 + 255) / 256, 256, 0, stream>>>(hp, ssbuf + l * 32, dinv,
                                                                  nxt, N);
        __half* tz = cur; cur = nxt; nxt = tz;
    }

    // heads: one traversal, dual epilogue into d_out
    gatherF_kernel<3><<<G, 256, 0, stream>>>(rowptr, col, cur, dinv,
                                             W_sin, W_cos, b_sin, b_cos,
                                             out, out + (size_t)N * DIM, nullptr,
                                             nullptr, N);
}